// Round 4
// baseline (648.419 us; speedup 1.0000x reference)
//
#include <hip/hip_runtime.h>
#include <hip/hip_bf16.h>
#include <math.h>

typedef __bf16 bf16;
typedef __bf16 bf16x8 __attribute__((ext_vector_type(8)));
typedef __bf16 bf16x4 __attribute__((ext_vector_type(4)));
typedef float  f32x4  __attribute__((ext_vector_type(4)));

#define D_MODEL 768
#define MLP_DIM 3072

// ---------------- workspace layout ---------------------------------------------
#define SZ_W1T   ((size_t)8*3072*768*2)        // bf16 [E][N=3072][K=768]
#define SZ_W2T   ((size_t)8*768*3072*2)        // bf16 [E][N=768][K=3072]
#define SZ_XED   ((size_t)8*8*256*768*2)       // bf16 [E][M=2048][768] det
#define SZ_XEC   ((size_t)8*8*32*768*2)        // cls
#define SZ_HD    ((size_t)8*2048*3072*2)       // bf16 [E][M][3072] det
#define SZ_HC    ((size_t)8*256*3072*2)        // cls
#define SZ_YED   ((size_t)8*2048*768*2)        // bf16 fc2 per-slot out det
#define SZ_YEC   ((size_t)8*256*768*2)         // cls
#define SZ_RID   ((size_t)8192*8)
#define SZ_RGD   ((size_t)8192*8)
#define SZ_RIC   ((size_t)1024*8)
#define SZ_RGC   ((size_t)1024*8)
#define SZ_STD   ((size_t)8*8*256*4)           // slot -> token (det)
#define SZ_STC   ((size_t)8*8*32*4)
#define SZ_TSD   ((size_t)2*8192*4)            // token,rank -> global slot (det)
#define SZ_TSC   ((size_t)2*1024*4)

#define OFF_W1T  ((size_t)0)
#define OFF_W2T  (OFF_W1T + SZ_W1T)
#define OFF_XED  (OFF_W2T + SZ_W2T)
#define OFF_XEC  (OFF_XED + SZ_XED)
#define OFF_HD   (OFF_XEC + SZ_XEC)
#define OFF_HC   (OFF_HD  + SZ_HD)
#define OFF_YED  (OFF_HC  + SZ_HC)
#define OFF_YEC  (OFF_YED + SZ_YED)
#define OFF_RID  (OFF_YEC + SZ_YEC)
#define OFF_RGD  (OFF_RID + SZ_RID)
#define OFF_RIC  (OFF_RGD + SZ_RGD)
#define OFF_RGC  (OFF_RIC + SZ_RIC)
#define OFF_STD  (OFF_RGC + SZ_RGC)
#define OFF_STC  (OFF_STD + SZ_STD)            // STD+STC contiguous: one memset(0xFF)
#define OFF_TSD  (OFF_STC + SZ_STC)
#define OFF_TSC  (OFF_TSD + SZ_TSD)

// ---------------- helpers ------------------------------------------------------
__device__ __forceinline__ void lds_load16(const void* g, void* l) {
  __builtin_amdgcn_global_load_lds((__attribute__((address_space(1))) void*)g,
                                   (__attribute__((address_space(3))) void*)l,
                                   16, 0, 0);
}

// tanh-gelu via exp: tanh(y) = 1 - 2/(e^{2y}+1). Saturates correctly at +/-inf.
__device__ __forceinline__ float gelu_fast(float x) {
  float y = 0.7978845608028654f * x * (1.f + 0.044715f * x * x);
  float e = __expf(2.f * y);
  float t = 1.f - 2.f / (e + 1.f);
  return 0.5f * x * (1.f + t);
}

// ---------------- router: gates = softmax(x@wr), top-2 -------------------------
__global__ void router_kernel(const float* __restrict__ x, const float* __restrict__ wr,
                              int ntok, int2* __restrict__ ridx, float2* __restrict__ rgate) {
  int wave = threadIdx.x >> 6;
  int lane = threadIdx.x & 63;
  int t = blockIdx.x * 4 + wave;
  if (t >= ntok) return;
  const float* xr = x + (size_t)t * D_MODEL;
  float acc[8];
#pragma unroll
  for (int e = 0; e < 8; ++e) acc[e] = 0.f;
  for (int d = lane; d < D_MODEL; d += 64) {
    float xv = xr[d];
    const float* w = wr + d * 8;
    float4 a = *(const float4*)w;
    float4 b = *(const float4*)(w + 4);
    acc[0] += xv * a.x; acc[1] += xv * a.y; acc[2] += xv * a.z; acc[3] += xv * a.w;
    acc[4] += xv * b.x; acc[5] += xv * b.y; acc[6] += xv * b.z; acc[7] += xv * b.w;
  }
#pragma unroll
  for (int off = 32; off > 0; off >>= 1) {
#pragma unroll
    for (int e = 0; e < 8; ++e) acc[e] += __shfl_xor(acc[e], off, 64);
  }
  float mx = acc[0];
#pragma unroll
  for (int e = 1; e < 8; ++e) mx = fmaxf(mx, acc[e]);
  float p[8]; float z = 0.f;
#pragma unroll
  for (int e = 0; e < 8; ++e) { p[e] = __expf(acc[e] - mx); z += p[e]; }
  int i1 = 0;
#pragma unroll
  for (int e = 1; e < 8; ++e) if (p[e] > p[i1]) i1 = e;
  int i2 = (i1 == 0) ? 1 : 0;
#pragma unroll
  for (int e = 0; e < 8; ++e) if (e != i1 && p[e] > p[i2]) i2 = e;
  if (lane == 0) {
    float inv = 1.f / z;
    ridx[t]  = make_int2(i1, i2);
    rgate[t] = make_float2(p[i1] * inv, p[i2] * inv);
  }
}

// ---------------- capacity positions + inverse (token -> slot) map -------------
// one wave per group; routing preloaded to LDS so the serial ballot phase
// doesn't eat a global-load latency per 64-token chunk
__global__ void positions_kernel(const int2* __restrict__ ridx,
                                 int* __restrict__ slot_token, int* __restrict__ tok_slot,
                                 int S, int C) {
  __shared__ int2 sh[1024];
  int g = blockIdx.x;
  int lane = threadIdx.x;
  int ntok = 8 * S;
  for (int i = lane; i < S; i += 64) sh[i] = ridx[g * S + i];
  __builtin_amdgcn_s_waitcnt(0);   // vmcnt(0)/lgkmcnt(0): single wave, no barrier needed
  unsigned long long ltmask = (1ull << lane) - 1ull;
  int cnt[8];
#pragma unroll
  for (int e = 0; e < 8; ++e) cnt[e] = 0;
  int nch = (2 * S) >> 6;
  for (int ch = 0; ch < nch; ++ch) {
    int a = (ch << 6) + lane;
    int r = (a >= S) ? 1 : 0;
    int s = a - r * S;
    int2 id = sh[s];
    int  e  = r ? id.y : id.x;
    unsigned long long mymask = 0;
    int add[8];
#pragma unroll
    for (int ee = 0; ee < 8; ++ee) {
      unsigned long long mk = __ballot(e == ee);
      if (e == ee) mymask = mk;
      add[ee] = __popcll(mk);
    }
    int pos = cnt[e] + __popcll(mymask & ltmask);
    int sl = (e * 8 + g) * C + pos;       // global slot id == e*M + (g*C+pos)
    if (pos < C) slot_token[sl] = s;
    tok_slot[r * ntok + g * S + s] = (pos < C) ? sl : -1;
#pragma unroll
    for (int ee = 0; ee < 8; ++ee) cnt[ee] += add[ee];
  }
}

// ---------------- gather tokens into dense bf16 expert buffers -----------------
// 256 threads: 4 slots per block
__global__ void gather_kernel(const float* __restrict__ x, const int* __restrict__ slot_token,
                              bf16* __restrict__ xe, int S, int C) {
  int slot = blockIdx.x * 4 + (threadIdx.x >> 6);
  int lane = threadIdx.x & 63;
  int g = (slot / C) & 7;
  int s = slot_token[slot];
  bf16* dst = xe + (size_t)slot * D_MODEL;
  const float* xr = x + ((size_t)g * S + (s < 0 ? 0 : s)) * D_MODEL;
#pragma unroll
  for (int j = 0; j < 3; ++j) {
    int idx = j * 256 + lane * 4;
    float4 v;
    if (s >= 0) v = *(const float4*)(xr + idx);
    else        v = make_float4(0.f, 0.f, 0.f, 0.f);
    bf16 o[4] = {(bf16)v.x, (bf16)v.y, (bf16)v.z, (bf16)v.w};
    *(uint2*)(dst + idx) = *(const uint2*)o;
  }
}

// ---------------- fp32 [E][K][N] -> bf16 [E][N][K] transpose -------------------
__global__ void convt_kernel(const float* __restrict__ src, bf16* __restrict__ dst, int K, int N) {
  __shared__ float tile[32][33];
  int e = blockIdx.z;
  const float* S_ = src + (size_t)e * K * N;
  bf16* D_ = dst + (size_t)e * K * N;
  int n0 = blockIdx.x * 32, k0 = blockIdx.y * 32;
  int tx = threadIdx.x, ty = threadIdx.y;
#pragma unroll
  for (int i = 0; i < 4; ++i)
    tile[ty + 8 * i][tx] = S_[(size_t)(k0 + ty + 8 * i) * N + (n0 + tx)];
  __syncthreads();
  int tid = ty * 32 + tx;
  int n = tid >> 3, kc = (tid & 7) * 4;
  bf16 o[4] = {(bf16)tile[kc][n], (bf16)tile[kc + 1][n], (bf16)tile[kc + 2][n], (bf16)tile[kc + 3][n]};
  *(uint2*)(D_ + (size_t)(n0 + n) * K + (k0 + kc)) = *(const uint2*)o;
}

// ---------------- combine: out[t] = sum_r gate_r * ye[slot_r] ------------------
// 256 threads: 4 tokens per block
__global__ void combine_kernel(const int* __restrict__ tok_slot, const float2* __restrict__ rgate,
                               const bf16* __restrict__ ye, float* __restrict__ out, int ntok) {
  int t = blockIdx.x * 4 + (threadIdx.x >> 6);
  int lane = threadIdx.x & 63;
  int s1 = tok_slot[t];
  int s2 = tok_slot[ntok + t];
  float2 gg = rgate[t];
  float g1 = (s1 < 0) ? 0.f : gg.x;
  float g2 = (s2 < 0) ? 0.f : gg.y;
  const bf16* y1 = ye + (size_t)(s1 < 0 ? 0 : s1) * D_MODEL;
  const bf16* y2 = ye + (size_t)(s2 < 0 ? 0 : s2) * D_MODEL;
  float* orow = out + (size_t)t * D_MODEL;
#pragma unroll
  for (int j = 0; j < 3; ++j) {
    int idx = j * 256 + lane * 4;
    bf16x4 a = *(const bf16x4*)(y1 + idx);
    bf16x4 b = *(const bf16x4*)(y2 + idx);
    float4 o;
    o.x = g1 * (float)a[0] + g2 * (float)b[0];
    o.y = g1 * (float)a[1] + g2 * (float)b[1];
    o.z = g1 * (float)a[2] + g2 * (float)b[2];
    o.w = g1 * (float)a[3] + g2 * (float)b[3];
    *(float4*)(orow + idx) = o;
  }
}

// ---------------- 128x128 bf16 MFMA GEMM, barrier-free K-loop ------------------
// A [E][M][K] bf16, Bt [E][N][K] bf16. Expert-per-XCD: e = bid&7.
// Each wave owns a 64x64 C-tile and stages its OWN 64x32 A and B sub-tiles into
// private double-buffered LDS via global_load_lds (8 ops/iter). No __syncthreads
// in the K-loop: each wave self-syncs with s_waitcnt vmcnt(8) (prefetch dist 1).
// LDS 64KB/block -> 2 blocks/CU; waves free-run, so collective barrier drains
// (the m97 ~20% stall) are gone entirely.
// det and cls problems merged into one launch (bid < splitd -> det).
template <int GELU>
__launch_bounds__(256, 2)
__global__ void gemm_mfma(const bf16* __restrict__ Adet, const bf16* __restrict__ Acls,
                          const bf16* __restrict__ Btall, const float* __restrict__ biasall,
                          int Mdet, int Mcls, int N, int K,
                          int Nmd, int Nmc, int Nn, int minner, int splitd,
                          bf16* __restrict__ Odet, bf16* __restrict__ Ocls) {
  int bid = blockIdx.x;
  const bf16* Aall; bf16* Oall; int M, Nm;
  if (bid < splitd) { Aall = Adet; Oall = Odet; M = Mdet; Nm = Nmd; }
  else { bid -= splitd; Aall = Acls; Oall = Ocls; M = Mcls; Nm = Nmc; }
  const int e   = bid & 7;                 // expert == XCD (blockIdx%8 heuristic)
  const int seq = bid >> 3;
  int m_t, n_t;
  if (minner) { n_t = seq / Nm; m_t = seq - n_t * Nm; }   // fc1: A_e resident in L2
  else        { m_t = seq / Nn; n_t = seq - m_t * Nn; }   // fc2: B_e resident in L2
  const int n0 = n_t * 128;
  const int m0 = m_t * 128;
  const int tid  = threadIdx.x;
  const int wave = tid >> 6, lane = tid & 63;
  const int wm = (wave >> 1) * 64, wn = (wave & 1) * 64;
  const int lrow = lane & 15, lquad = lane >> 4;

  // per-wave private region: 2 bufs x (A 64x32 + B 64x32) = 16KB; 4 waves = 64KB
  __shared__ __align__(16) bf16 smem[32768];
  bf16* wbase = smem + wave * 8192;

  // wave's global sub-tile bases (rows m0+wm.., n0+wn..)
  const bf16* Aw = Aall  + (size_t)e * M * K + (size_t)(m0 + wm) * K;
  const bf16* Bw = Btall + (size_t)e * N * K + (size_t)(n0 + wn) * K;
  // per-lane source offsets: row = j*16 + (lane>>2), 16B chunk = lane&3
  const size_t rowoff = (size_t)(lane >> 2) * K;
  const int    choff  = (lane & 3) * 8;

  // bias fragment (4 cols per lane)
  const float* bias = biasall + (size_t)e * N;
  float bfr[4];
#pragma unroll
  for (int ni = 0; ni < 4; ++ni) bfr[ni] = bias[n0 + wn + ni * 16 + lrow];

  f32x4 acc[4][4];
#pragma unroll
  for (int mi = 0; mi < 4; ++mi)
#pragma unroll
    for (int ni = 0; ni < 4; ++ni) acc[mi][ni] = {0.f, 0.f, 0.f, 0.f};

  const int nsteps = K >> 5;
  // stage(kt, buf): 8 lds_load16 (A then B interleaved), 1KB each
#define STAGE(ktv, bufv)                                                        \
  {                                                                             \
    const bf16* as_ = Aw + (ktv) * 32 + choff + rowoff;                         \
    const bf16* bs_ = Bw + (ktv) * 32 + choff + rowoff;                         \
    bf16* al_ = wbase + (bufv) * 2048;                                          \
    bf16* bl_ = wbase + 4096 + (bufv) * 2048;                                   \
    _Pragma("unroll")                                                           \
    for (int j = 0; j < 4; ++j) {                                               \
      lds_load16(as_ + (size_t)(j * 16) * K, al_ + j * 512);                    \
      lds_load16(bs_ + (size_t)(j * 16) * K, bl_ + j * 512);                    \
    }                                                                           \
  }

  STAGE(0, 0);
#pragma unroll 2
  for (int kt = 0; kt < nsteps; ++kt) {
    const int cb = kt & 1;
    const int nx = (kt + 1 < nsteps) ? kt + 1 : 0;   // wrap keeps vmcnt count exact
    STAGE(nx, cb ^ 1);
    asm volatile("s_waitcnt vmcnt(8)" ::: "memory");  // own stage(kt) landed
    const bf16* al = wbase + cb * 2048;
    const bf16* bl = wbase + 4096 + cb * 2048;
    bf16x8 fa[4], fb[4];
#pragma unroll
    for (int i = 0; i < 4; ++i) {
      fa[i] = *(const bf16x8*)(al + (i * 16 + lrow) * 32 + lquad * 8);
      fb[i] = *(const bf16x8*)(bl + (i * 16 + lrow) * 32 + lquad * 8);
    }
#pragma unroll
    for (int mi = 0; mi < 4; ++mi)
#pragma unroll
      for (int ni = 0; ni < 4; ++ni)
        acc[mi][ni] = __builtin_amdgcn_mfma_f32_16x16x32_bf16(fa[mi], fb[ni], acc[mi][ni], 0, 0, 0);
  }
#undef STAGE

  // ---- epilogue: acc -> LDS (first 32KB) -> coalesced b128 global stores ------
  __syncthreads();   // drains in-flight wrap-prefetch DMA (vmcnt0) + joins waves
#pragma unroll
  for (int mi = 0; mi < 4; ++mi) {
#pragma unroll
    for (int r = 0; r < 4; ++r) {
      int row = wm + mi * 16 + lquad * 4 + r;
#pragma unroll
      for (int ni = 0; ni < 4; ++ni) {
        int colL = wn + ni * 16 + lrow;
        float v = acc[mi][ni][r] + bfr[ni];
        if (GELU) v = gelu_fast(v);
        int chunk = (colL >> 3) ^ (row & 7);           // 16B-chunk swizzle
        smem[row * 128 + chunk * 8 + (colL & 7)] = (bf16)v;
      }
    }
  }
  __syncthreads();
  bf16* O = Oall + (size_t)e * M * N;
#pragma unroll
  for (int it = 0; it < 8; ++it) {
    int idx = it * 256 + tid;          // 0..2047
    int row = idx >> 4;                // 0..127
    int ck  = idx & 15;
    int pchunk = ck ^ (row & 7);
    bf16x8 vv = *(const bf16x8*)(smem + row * 128 + pchunk * 8);
    *(bf16x8*)(O + (size_t)(m0 + row) * N + n0 + ck * 8) = vv;
  }
}

// ---------------- launch -------------------------------------------------------
extern "C" void kernel_launch(void* const* d_in, const int* in_sizes, int n_in,
                              void* d_out, int out_size, void* d_ws, size_t ws_size,
                              hipStream_t stream) {
  (void)in_sizes; (void)n_in; (void)ws_size; (void)out_size;
  const float* x_det  = (const float*)d_in[0];
  const float* x_cls  = (const float*)d_in[1];
  const float* wr_det = (const float*)d_in[2];
  const float* wr_cls = (const float*)d_in[3];
  const float* w1     = (const float*)d_in[4];
  const float* b1     = (const float*)d_in[5];
  const float* w2     = (const float*)d_in[6];
  const float* b2     = (const float*)d_in[7];
  float* out = (float*)d_out;
  char*  ws  = (char*)d_ws;

  bf16*   w1t    = (bf16*)(ws + OFF_W1T);
  bf16*   w2t    = (bf16*)(ws + OFF_W2T);
  bf16*   xe_det = (bf16*)(ws + OFF_XED);
  bf16*   xe_cls = (bf16*)(ws + OFF_XEC);
  bf16*   h_det  = (bf16*)(ws + OFF_HD);
  bf16*   h_cls  = (bf16*)(ws + OFF_HC);
  bf16*   ye_det = (bf16*)(ws + OFF_YED);
  bf16*   ye_cls = (bf16*)(ws + OFF_YEC);
  int2*   ri_det = (int2*)(ws + OFF_RID);
  float2* rg_det = (float2*)(ws + OFF_RGD);
  int2*   ri_cls = (int2*)(ws + OFF_RIC);
  float2* rg_cls = (float2*)(ws + OFF_RGC);
  int*    st_det = (int*)(ws + OFF_STD);
  int*    st_cls = (int*)(ws + OFF_STC);
  int*    ts_det = (int*)(ws + OFF_TSD);
  int*    ts_cls = (int*)(ws + OFF_TSC);

  // empty slots -> -1 (STD+STC contiguous)
  hipMemsetAsync(ws + OFF_STD, 0xFF, SZ_STD + SZ_STC, stream);

  // weights: fp32 [E][K][N] -> bf16 [E][N][K]
  convt_kernel<<<dim3(3072 / 32, 768 / 32, 8), dim3(32, 8), 0, stream>>>(w1, w1t, 768, 3072);
  convt_kernel<<<dim3(768 / 32, 3072 / 32, 8), dim3(32, 8), 0, stream>>>(w2, w2t, 3072, 768);

  // routing
  router_kernel<<<8192 / 4, 256, 0, stream>>>(x_det, wr_det, 8192, ri_det, rg_det);
  router_kernel<<<1024 / 4, 256, 0, stream>>>(x_cls, wr_cls, 1024, ri_cls, rg_cls);
  positions_kernel<<<8, 64, 0, stream>>>(ri_det, st_det, ts_det, 1024, 256);
  positions_kernel<<<8, 64, 0, stream>>>(ri_cls, st_cls, ts_cls, 128, 32);

  // gather to dense expert buffers (bf16)
  gather_kernel<<<8 * 8 * 256 / 4, 256, 0, stream>>>(x_det, st_det, xe_det, 1024, 256);
  gather_kernel<<<8 * 8 * 32 / 4, 256, 0, stream>>>(x_cls, st_cls, xe_cls, 128, 32);

  // fc1 (det+cls merged): h = gelu(xe @ w1 + b1); n-outer/m-inner (A_e in L2)
  gemm_mfma<1><<<8 * 16 * 24 + 8 * 2 * 24, 256, 0, stream>>>(
      xe_det, xe_cls, w1t, b1, 2048, 256, 3072, 768,
      16, 2, 24, 1, 8 * 16 * 24, h_det, h_cls);

  // fc2 (det+cls merged): ye = h @ w2 + b2; m-outer/n-inner (B_e in L2)
  gemm_mfma<0><<<8 * 16 * 6 + 8 * 2 * 6, 256, 0, stream>>>(
      h_det, h_cls, w2t, b2, 2048, 256, 768, 3072,
      16, 2, 6, 0, 8 * 16 * 6, ye_det, ye_cls);

  // combine: out[t] = sum_r gate_r * ye[slot_r]
  combine_kernel<<<8192 / 4, 256, 0, stream>>>(ts_det, rg_det, ye_det, out, 8192);
  combine_kernel<<<1024 / 4, 256, 0, stream>>>(ts_cls, rg_cls, ye_cls, out + (size_t)8192 * 768, 1024);
}

// Round 5
// 478.827 us; speedup vs baseline: 1.3542x; 1.3542x over previous
//
#include <hip/hip_runtime.h>
#include <hip/hip_bf16.h>
#include <math.h>

typedef __bf16 bf16;
typedef __bf16 bf16x8 __attribute__((ext_vector_type(8)));
typedef __bf16 bf16x4 __attribute__((ext_vector_type(4)));
typedef float  f32x4  __attribute__((ext_vector_type(4)));

#define D_MODEL 768
#define MLP_DIM 3072

// ---------------- workspace layout ---------------------------------------------
#define SZ_W1T   ((size_t)8*3072*768*2)        // bf16 [E][N=3072][K=768]
#define SZ_W2T   ((size_t)8*768*3072*2)        // bf16 [E][N=768][K=3072]
#define SZ_XED   ((size_t)8*8*256*768*2)       // bf16 [E][M=2048][768] det
#define SZ_XEC   ((size_t)8*8*32*768*2)        // cls
#define SZ_HD    ((size_t)8*2048*3072*2)       // bf16 [E][M][3072] det
#define SZ_HC    ((size_t)8*256*3072*2)        // cls
#define SZ_YED   ((size_t)8*2048*768*2)        // bf16 fc2 per-slot out det
#define SZ_YEC   ((size_t)8*256*768*2)         // cls
#define SZ_RID   ((size_t)8192*8)
#define SZ_RGD   ((size_t)8192*8)
#define SZ_RIC   ((size_t)1024*8)
#define SZ_RGC   ((size_t)1024*8)
#define SZ_STD   ((size_t)8*8*256*4)           // slot -> token (det)
#define SZ_STC   ((size_t)8*8*32*4)
#define SZ_TSD   ((size_t)2*8192*4)            // token,rank -> global slot (det)
#define SZ_TSC   ((size_t)2*1024*4)

#define OFF_W1T  ((size_t)0)
#define OFF_W2T  (OFF_W1T + SZ_W1T)
#define OFF_XED  (OFF_W2T + SZ_W2T)
#define OFF_XEC  (OFF_XED + SZ_XED)
#define OFF_HD   (OFF_XEC + SZ_XEC)
#define OFF_HC   (OFF_HD  + SZ_HD)
#define OFF_YED  (OFF_HC  + SZ_HC)
#define OFF_YEC  (OFF_YED + SZ_YED)
#define OFF_RID  (OFF_YEC + SZ_YEC)
#define OFF_RGD  (OFF_RID + SZ_RID)
#define OFF_RIC  (OFF_RGD + SZ_RGD)
#define OFF_RGC  (OFF_RIC + SZ_RIC)
#define OFF_STD  (OFF_RGC + SZ_RGC)
#define OFF_STC  (OFF_STD + SZ_STD)            // STD+STC contiguous: one memset(0xFF)
#define OFF_TSD  (OFF_STC + SZ_STC)
#define OFF_TSC  (OFF_TSD + SZ_TSD)

// ---------------- helpers ------------------------------------------------------
__device__ __forceinline__ void lds_load16(const void* g, void* l) {
  __builtin_amdgcn_global_load_lds((__attribute__((address_space(1))) void*)g,
                                   (__attribute__((address_space(3))) void*)l,
                                   16, 0, 0);
}

// tanh-gelu via exp: tanh(y) = 1 - 2/(e^{2y}+1). Saturates correctly at +/-inf.
__device__ __forceinline__ float gelu_fast(float x) {
  float y = 0.7978845608028654f * x * (1.f + 0.044715f * x * x);
  float e = __expf(2.f * y);
  float t = 1.f - 2.f / (e + 1.f);
  return 0.5f * x * (1.f + t);
}

// ---------------- router (det+cls merged): softmax(x@wr), top-2 ----------------
__global__ void router_kernel(const float* __restrict__ xd, const float* __restrict__ wrd,
                              const float* __restrict__ xc, const float* __restrict__ wrc,
                              int2* __restrict__ rid, float2* __restrict__ rgd,
                              int2* __restrict__ ric, float2* __restrict__ rgc,
                              int splitd) {
  int bid = blockIdx.x;
  const float *x, *wr; int2* ridx; float2* rgate;
  if (bid < splitd) { x = xd; wr = wrd; ridx = rid; rgate = rgd; }
  else { bid -= splitd; x = xc; wr = wrc; ridx = ric; rgate = rgc; }
  int wave = threadIdx.x >> 6;
  int lane = threadIdx.x & 63;
  int t = bid * 4 + wave;
  const float* xr = x + (size_t)t * D_MODEL;
  float acc[8];
#pragma unroll
  for (int e = 0; e < 8; ++e) acc[e] = 0.f;
  for (int d = lane; d < D_MODEL; d += 64) {
    float xv = xr[d];
    const float* w = wr + d * 8;
    float4 a = *(const float4*)w;
    float4 b = *(const float4*)(w + 4);
    acc[0] += xv * a.x; acc[1] += xv * a.y; acc[2] += xv * a.z; acc[3] += xv * a.w;
    acc[4] += xv * b.x; acc[5] += xv * b.y; acc[6] += xv * b.z; acc[7] += xv * b.w;
  }
#pragma unroll
  for (int off = 32; off > 0; off >>= 1) {
#pragma unroll
    for (int e = 0; e < 8; ++e) acc[e] += __shfl_xor(acc[e], off, 64);
  }
  float mx = acc[0];
#pragma unroll
  for (int e = 1; e < 8; ++e) mx = fmaxf(mx, acc[e]);
  float p[8]; float z = 0.f;
#pragma unroll
  for (int e = 0; e < 8; ++e) { p[e] = __expf(acc[e] - mx); z += p[e]; }
  int i1 = 0;
#pragma unroll
  for (int e = 1; e < 8; ++e) if (p[e] > p[i1]) i1 = e;
  int i2 = (i1 == 0) ? 1 : 0;
#pragma unroll
  for (int e = 0; e < 8; ++e) if (e != i1 && p[e] > p[i2]) i2 = e;
  if (lane == 0) {
    float inv = 1.f / z;
    ridx[t]  = make_int2(i1, i2);
    rgate[t] = make_float2(p[i1] * inv, p[i2] * inv);
  }
}

// ---------------- capacity positions + inverse map (det+cls merged) ------------
// one wave per group; routing preloaded to LDS
__global__ void positions_kernel(const int2* __restrict__ rid, int* __restrict__ std_,
                                 int* __restrict__ tsd_, const int2* __restrict__ ric,
                                 int* __restrict__ stc_, int* __restrict__ tsc_) {
  __shared__ int2 sh[1024];
  int bid = blockIdx.x;
  const int2* ridx; int *slot_token, *tok_slot; int S, C, g;
  if (bid < 8) { ridx = rid; slot_token = std_; tok_slot = tsd_; S = 1024; C = 256; g = bid; }
  else { ridx = ric; slot_token = stc_; tok_slot = tsc_; S = 128; C = 32; g = bid - 8; }
  int lane = threadIdx.x;
  int ntok = 8 * S;
  for (int i = lane; i < S; i += 64) sh[i] = ridx[g * S + i];
  __builtin_amdgcn_s_waitcnt(0);   // single wave: no barrier needed
  unsigned long long ltmask = (1ull << lane) - 1ull;
  int cnt[8];
#pragma unroll
  for (int e = 0; e < 8; ++e) cnt[e] = 0;
  int nch = (2 * S) >> 6;
  for (int ch = 0; ch < nch; ++ch) {
    int a = (ch << 6) + lane;
    int r = (a >= S) ? 1 : 0;
    int s = a - r * S;
    int2 id = sh[s];
    int  e  = r ? id.y : id.x;
    unsigned long long mymask = 0;
    int add[8];
#pragma unroll
    for (int ee = 0; ee < 8; ++ee) {
      unsigned long long mk = __ballot(e == ee);
      if (e == ee) mymask = mk;
      add[ee] = __popcll(mk);
    }
    int pos = cnt[e] + __popcll(mymask & ltmask);
    int sl = (e * 8 + g) * C + pos;       // global slot id == e*M + (g*C+pos)
    if (pos < C) slot_token[sl] = s;
    tok_slot[r * ntok + g * S + s] = (pos < C) ? sl : -1;
#pragma unroll
    for (int ee = 0; ee < 8; ++ee) cnt[ee] += add[ee];
  }
}

// ---------------- gather (det+cls merged): 4 slots per block -------------------
__global__ void gather_kernel(const float* __restrict__ xd, const int* __restrict__ std_,
                              bf16* __restrict__ xed, const float* __restrict__ xc,
                              const int* __restrict__ stc_, bf16* __restrict__ xec,
                              int splitd) {
  int bid = blockIdx.x;
  const float* x; const int* slot_token; bf16* xe; int S, C;
  if (bid < splitd) { x = xd; slot_token = std_; xe = xed; S = 1024; C = 256; }
  else { bid -= splitd; x = xc; slot_token = stc_; xe = xec; S = 128; C = 32; }
  int slot = bid * 4 + (threadIdx.x >> 6);
  int lane = threadIdx.x & 63;
  int g = (slot / C) & 7;
  int s = slot_token[slot];
  bf16* dst = xe + (size_t)slot * D_MODEL;
  const float* xr = x + ((size_t)g * S + (s < 0 ? 0 : s)) * D_MODEL;
#pragma unroll
  for (int j = 0; j < 3; ++j) {
    int idx = j * 256 + lane * 4;
    float4 v;
    if (s >= 0) v = *(const float4*)(xr + idx);
    else        v = make_float4(0.f, 0.f, 0.f, 0.f);
    bf16 o[4] = {(bf16)v.x, (bf16)v.y, (bf16)v.z, (bf16)v.w};
    *(uint2*)(dst + idx) = *(const uint2*)o;
  }
}

// ---------------- w1+w2 merged: fp32 [E][K][N] -> bf16 [E][N][K] ---------------
// part 0: w1 (K=768,N=3072); part 1: w2 (K=3072,N=768). 2304 tiles/expert each.
__global__ void convt_kernel(const float* __restrict__ w1, bf16* __restrict__ w1t,
                             const float* __restrict__ w2, bf16* __restrict__ w2t) {
  __shared__ float tile[32][33];
  int bid = blockIdx.x;
  const float* src; bf16* dst; int K, N;
  if (bid < 18432) { src = w1; dst = w1t; K = 768; N = 3072; }
  else { bid -= 18432; src = w2; dst = w2t; K = 3072; N = 768; }
  int e = bid / 2304;
  int t = bid - e * 2304;
  int tiles_x = N >> 5;
  int ky = t / tiles_x;
  int n0 = (t - ky * tiles_x) * 32, k0 = ky * 32;
  const float* S_ = src + (size_t)e * K * N;
  bf16* D_ = dst + (size_t)e * K * N;
  int tx = threadIdx.x & 31, ty = threadIdx.x >> 5;
#pragma unroll
  for (int i = 0; i < 4; ++i)
    tile[ty + 8 * i][tx] = S_[(size_t)(k0 + ty + 8 * i) * N + (n0 + tx)];
  __syncthreads();
  int tid = threadIdx.x;
  int n = tid >> 3, kc = (tid & 7) * 4;
  bf16 o[4] = {(bf16)tile[kc][n], (bf16)tile[kc + 1][n], (bf16)tile[kc + 2][n], (bf16)tile[kc + 3][n]};
  *(uint2*)(D_ + (size_t)(n0 + n) * K + (k0 + kc)) = *(const uint2*)o;
}

// ---------------- combine (det+cls merged): 4 tokens per block -----------------
__global__ void combine_kernel(const int* __restrict__ tsd_, const float2* __restrict__ rgd,
                               const bf16* __restrict__ yed, float* __restrict__ outd,
                               const int* __restrict__ tsc_, const float2* __restrict__ rgc,
                               const bf16* __restrict__ yec, float* __restrict__ outc,
                               int splitd) {
  int bid = blockIdx.x;
  const int* tok_slot; const float2* rgate; const bf16* ye; float* out; int ntok;
  if (bid < splitd) { tok_slot = tsd_; rgate = rgd; ye = yed; out = outd; ntok = 8192; }
  else { bid -= splitd; tok_slot = tsc_; rgate = rgc; ye = yec; out = outc; ntok = 1024; }
  int t = bid * 4 + (threadIdx.x >> 6);
  int lane = threadIdx.x & 63;
  int s1 = tok_slot[t];
  int s2 = tok_slot[ntok + t];
  float2 gg = rgate[t];
  float g1 = (s1 < 0) ? 0.f : gg.x;
  float g2 = (s2 < 0) ? 0.f : gg.y;
  const bf16* y1 = ye + (size_t)(s1 < 0 ? 0 : s1) * D_MODEL;
  const bf16* y2 = ye + (size_t)(s2 < 0 ? 0 : s2) * D_MODEL;
  float* orow = out + (size_t)t * D_MODEL;
#pragma unroll
  for (int j = 0; j < 3; ++j) {
    int idx = j * 256 + lane * 4;
    bf16x4 a = *(const bf16x4*)(y1 + idx);
    bf16x4 b = *(const bf16x4*)(y2 + idx);
    float4 o;
    o.x = g1 * (float)a[0] + g2 * (float)b[0];
    o.y = g1 * (float)a[1] + g2 * (float)b[1];
    o.z = g1 * (float)a[2] + g2 * (float)b[2];
    o.w = g1 * (float)a[3] + g2 * (float)b[3];
    *(float4*)(orow + idx) = o;
  }
}

// ---------------- 128x128 bf16 MFMA GEMM, BK=64 collective staging -------------
// R3's proven 2-barrier structure, BK doubled 32->64: barrier crossings halve
// (fc1 24->12, fc2 96->48) at the same 32KB LDS / 3 blocks/CU.
// Rows are 128B; staging fetches global chunk (c ^ (row&7)) into LDS slot c
// (swizzle on the GLOBAL address -- global_load_lds LDS side is fixed lane*16),
// so fragment b128 reads hit all 8 bank-quads with 2 lanes each (2-way = free).
// det and cls merged into one launch (bid < splitd -> det).
template <int GELU>
__launch_bounds__(256, 3)
__global__ void gemm_mfma(const bf16* __restrict__ Adet, const bf16* __restrict__ Acls,
                          const bf16* __restrict__ Btall, const float* __restrict__ biasall,
                          int Mdet, int Mcls, int N, int K,
                          int Nmd, int Nmc, int Nn, int minner, int splitd,
                          bf16* __restrict__ Odet, bf16* __restrict__ Ocls) {
  int bid = blockIdx.x;
  const bf16* Aall; bf16* Oall; int M, Nm;
  if (bid < splitd) { Aall = Adet; Oall = Odet; M = Mdet; Nm = Nmd; }
  else { bid -= splitd; Aall = Acls; Oall = Ocls; M = Mcls; Nm = Nmc; }
  const int e   = bid & 7;                 // expert == XCD (blockIdx%8 heuristic)
  const int seq = bid >> 3;
  int m_t, n_t;
  if (minner) { n_t = seq / Nm; m_t = seq - n_t * Nm; }   // fc1: A_e resident in L2
  else        { m_t = seq / Nn; n_t = seq - m_t * Nn; }   // fc2: B_e resident in L2
  const int n0 = n_t * 128;
  const int m0 = m_t * 128;
  const int tid  = threadIdx.x;
  const int wave = tid >> 6, lane = tid & 63;
  const int wm = (wave >> 1) * 64, wn = (wave & 1) * 64;
  const int lrow = lane & 15, lquad = lane >> 4;

  // 32 KB: K-loop A(16KB)|B(16KB); epilogue reuses all 32 KB as 128x128 C-tile
  __shared__ __align__(16) bf16 smem[16384];
  bf16* As = smem;
  bf16* Bs = smem + 8192;

  const bf16* A  = Aall  + (size_t)e * M * K;
  const bf16* Bt = Btall + (size_t)e * N * K;

  // staging: 4 rounds x 32 rows x 8 chunks(16B) per 16KB tile
  const int srow = tid >> 3;                         // 0..31
  const int gq   = (tid & 7) ^ (srow & 7);           // global chunk (swizzled)
  const bf16* Asrc = A  + (size_t)(m0 + srow) * K + gq * 8;
  const bf16* Bsrc = Bt + (size_t)(n0 + srow) * K + gq * 8;
  char* AsB = (char*)As;
  char* BsB = (char*)Bs;
  const int ldsw = wave * 1024;                      // wave-uniform (+lane*16 HW)

  // bias fragment (4 cols per lane)
  const float* bias = biasall + (size_t)e * N;
  float bfr[4];
#pragma unroll
  for (int ni = 0; ni < 4; ++ni) bfr[ni] = bias[n0 + wn + ni * 16 + lrow];

  f32x4 acc[4][4];
#pragma unroll
  for (int mi = 0; mi < 4; ++mi)
#pragma unroll
    for (int ni = 0; ni < 4; ++ni) acc[mi][ni] = {0.f, 0.f, 0.f, 0.f};

  const int xsw = lrow & 7;                          // fragment chunk de-swizzle
  const int nsteps = K >> 6;
  for (int kt = 0; kt < nsteps; ++kt) {
    const bf16* a0 = Asrc + kt * 64;
    const bf16* b0 = Bsrc + kt * 64;
#pragma unroll
    for (int rd = 0; rd < 4; ++rd) {
      lds_load16(a0 + (size_t)(rd * 32) * K, AsB + rd * 4096 + ldsw);
      lds_load16(b0 + (size_t)(rd * 32) * K, BsB + rd * 4096 + ldsw);
    }
    __syncthreads();
#pragma unroll
    for (int h = 0; h < 2; ++h) {
      bf16x8 fa[4], fb[4];
      const int ca = ((h * 4 + lquad) ^ xsw) * 8;
#pragma unroll
      for (int i = 0; i < 4; ++i) {
        fa[i] = *(const bf16x8*)(As + (wm + i * 16 + lrow) * 64 + ca);
        fb[i] = *(const bf16x8*)(Bs + (wn + i * 16 + lrow) * 64 + ca);
      }
#pragma unroll
      for (int mi = 0; mi < 4; ++mi)
#pragma unroll
        for (int ni = 0; ni < 4; ++ni)
          acc[mi][ni] = __builtin_amdgcn_mfma_f32_16x16x32_bf16(fa[mi], fb[ni], acc[mi][ni], 0, 0, 0);
    }
    __syncthreads();
  }

  // ---- epilogue: acc -> LDS (swizzled) -> coalesced b128 global stores --------
  // C/D layout: col = lane&15 (+16*ni), row = lquad*4 + r (+16*mi)
#pragma unroll
  for (int mi = 0; mi < 4; ++mi) {
#pragma unroll
    for (int r = 0; r < 4; ++r) {
      int row = wm + mi * 16 + lquad * 4 + r;
#pragma unroll
      for (int ni = 0; ni < 4; ++ni) {
        int colL = wn + ni * 16 + lrow;
        float v = acc[mi][ni][r] + bfr[ni];
        if (GELU) v = gelu_fast(v);
        int chunk = (colL >> 3) ^ (row & 7);           // 16B-chunk swizzle
        smem[row * 128 + chunk * 8 + (colL & 7)] = (bf16)v;
      }
    }
  }
  __syncthreads();
  bf16* O = Oall + (size_t)e * M * N;
#pragma unroll
  for (int it = 0; it < 8; ++it) {
    int idx = it * 256 + tid;          // 0..2047
    int row = idx >> 4;                // 0..127
    int ck  = idx & 15;
    int pchunk = ck ^ (row & 7);
    bf16x8 vv = *(const bf16x8*)(smem + row * 128 + pchunk * 8);
    *(bf16x8*)(O + (size_t)(m0 + row) * N + n0 + ck * 8) = vv;
  }
}

// ---------------- launch -------------------------------------------------------
extern "C" void kernel_launch(void* const* d_in, const int* in_sizes, int n_in,
                              void* d_out, int out_size, void* d_ws, size_t ws_size,
                              hipStream_t stream) {
  (void)in_sizes; (void)n_in; (void)ws_size; (void)out_size;
  const float* x_det  = (const float*)d_in[0];
  const float* x_cls  = (const float*)d_in[1];
  const float* wr_det = (const float*)d_in[2];
  const float* wr_cls = (const float*)d_in[3];
  const float* w1     = (const float*)d_in[4];
  const float* b1     = (const float*)d_in[5];
  const float* w2     = (const float*)d_in[6];
  const float* b2     = (const float*)d_in[7];
  float* out = (float*)d_out;
  char*  ws  = (char*)d_ws;

  bf16*   w1t    = (bf16*)(ws + OFF_W1T);
  bf16*   w2t    = (bf16*)(ws + OFF_W2T);
  bf16*   xe_det = (bf16*)(ws + OFF_XED);
  bf16*   xe_cls = (bf16*)(ws + OFF_XEC);
  bf16*   h_det  = (bf16*)(ws + OFF_HD);
  bf16*   h_cls  = (bf16*)(ws + OFF_HC);
  bf16*   ye_det = (bf16*)(ws + OFF_YED);
  bf16*   ye_cls = (bf16*)(ws + OFF_YEC);
  int2*   ri_det = (int2*)(ws + OFF_RID);
  float2* rg_det = (float2*)(ws + OFF_RGD);
  int2*   ri_cls = (int2*)(ws + OFF_RIC);
  float2* rg_cls = (float2*)(ws + OFF_RGC);
  int*    st_det = (int*)(ws + OFF_STD);
  int*    st_cls = (int*)(ws + OFF_STC);
  int*    ts_det = (int*)(ws + OFF_TSD);
  int*    ts_cls = (int*)(ws + OFF_TSC);

  // empty slots -> -1 (STD+STC contiguous)
  hipMemsetAsync(ws + OFF_STD, 0xFF, SZ_STD + SZ_STC, stream);

  // weights (w1+w2 merged): fp32 [E][K][N] -> bf16 [E][N][K]
  convt_kernel<<<2 * 18432, 256, 0, stream>>>(w1, w1t, w2, w2t);

  // routing (det+cls merged)
  router_kernel<<<2048 + 256, 256, 0, stream>>>(x_det, wr_det, x_cls, wr_cls,
                                                ri_det, rg_det, ri_cls, rg_cls, 2048);
  positions_kernel<<<16, 64, 0, stream>>>(ri_det, st_det, ts_det, ri_cls, st_cls, ts_cls);

  // gather to dense expert buffers (det+cls merged)
  gather_kernel<<<4096 + 512, 256, 0, stream>>>(x_det, st_det, xe_det, x_cls, st_cls, xe_cls, 4096);

  // fc1 (det+cls merged): h = gelu(xe @ w1 + b1); n-outer/m-inner (A_e in L2)
  gemm_mfma<1><<<8 * 16 * 24 + 8 * 2 * 24, 256, 0, stream>>>(
      xe_det, xe_cls, w1t, b1, 2048, 256, 3072, 768,
      16, 2, 24, 1, 8 * 16 * 24, h_det, h_cls);

  // fc2 (det+cls merged): ye = h @ w2 + b2; m-outer/n-inner (B_e in L2)
  gemm_mfma<0><<<8 * 16 * 6 + 8 * 2 * 6, 256, 0, stream>>>(
      h_det, h_cls, w2t, b2, 2048, 256, 768, 3072,
      16, 2, 6, 0, 8 * 16 * 6, ye_det, ye_cls);

  // combine (det+cls merged): out[t] = sum_r gate_r * ye[slot_r]
  combine_kernel<<<2048 + 256, 256, 0, stream>>>(ts_det, rg_det, ye_det, out,
                                                 ts_cls, rg_cls, ye_cls,
                                                 out + (size_t)8192 * 768, 2048);
}